// Round 8
// baseline (659.943 us; speedup 1.0000x reference)
//
#include <hip/hip_runtime.h>
#include <stdint.h>

#define TT 300
#define NLW 32               // launched WGs (election pool)

// ws layout (floats)
#define XW0_OFF 0
#define XW0_SZ  (TT*4*1024)
#define HQ0_OFF (XW0_OFF + XW0_SZ)
#define HQ_SZ   (TT*1024*2)          // {h,tag} pairs, 2 floats each
#define HQ1_OFF (HQ0_OFF + HQ_SZ)
#define EL_OFF  (HQ1_OFF + HQ_SZ)    // election scoreboard: NLW ints (in pairs)
#define NZPAIRS (TT*1024*2 + NLW)    // pairs zeroed each launch (hq0+hq1+elect)

typedef _Float16 f16x8 __attribute__((ext_vector_type(8)));
typedef float    f32x4 __attribute__((ext_vector_type(4)));

__device__ __forceinline__ float sigf(float x){ return 1.0f/(1.0f+__expf(-x)); }
__device__ __forceinline__ float tahf(float x){ return 1.0f-2.0f/(__expf(2.0f*x)+1.0f); }

// ---- memory primitives ----------------------------------------------------
// LLC-coherent 16B load (bypass L1+L2)
__device__ __forceinline__ uint4 ld16_llc(const float* p) {
  uint4 v;
  asm volatile("global_load_dwordx4 %0, %1, off sc0 sc1\n\t"
               "s_waitcnt vmcnt(0)"
               : "=v"(v) : "v"(p) : "memory");
  return v;
}
// L2-coherent 16B load (bypass L1 only; hits the XCD's shared L2)
__device__ __forceinline__ uint4 ld16_sc0(const float* p) {
  uint4 v;
  asm volatile("global_load_dwordx4 %0, %1, off sc0\n\t"
               "s_waitcnt vmcnt(0)"
               : "=v"(v) : "v"(p) : "memory");
  return v;
}
__device__ __forceinline__ int ld_i32_llc(const int* p) {
  int v;
  asm volatile("global_load_dword %0, %1, off sc0 sc1\n\t"
               "s_waitcnt vmcnt(0)"
               : "=v"(v) : "v"(p) : "memory");
  return v;
}
// packed {h,tag} 8B: dual store — sc0 (fast, shared L2) + sc1 (LLC, fallback)
__device__ __forceinline__ void store_pair_dual(float* p, float h, unsigned tag) {
  union { struct { float h; unsigned t; } s; unsigned long long u; uint2 d; } pk;
  pk.s.h = h; pk.s.t = tag;
  asm volatile("global_store_dwordx2 %0, %1, off sc0"
               :: "v"(p), "v"(pk.d) : "memory");
  __hip_atomic_store((unsigned long long*)p, pk.u,
                     __ATOMIC_RELAXED, __HIP_MEMORY_SCOPE_AGENT);
}
// LLC-only pair store (zeroing)
__device__ __forceinline__ void store_pair_llc(float* p, float h, unsigned tag) {
  union { struct { float h; unsigned t; } s; unsigned long long u; } pk;
  pk.s.h = h; pk.s.t = tag;
  __hip_atomic_store((unsigned long long*)p, pk.u,
                     __ATOMIC_RELAXED, __HIP_MEMORY_SCOPE_AGENT);
}
// fast poll: sc0 period (~L2 RT), sc1 check every 4th iter (cross-XCD rescue)
__device__ __forceinline__ uint4 poll_pair16(const float* p, unsigned tg) {
  uint4 q;
  for (unsigned it = 0; ; ++it) {
    q = ld16_sc0(p);
    if (q.y == tg && q.w == tg) break;
    if ((it & 3) == 3) { q = ld16_llc(p); if (q.y == tg && q.w == tg) break; }
    if (it > (1u<<20)) break;
  }
  return q;
}
// joint poll: h1 via sc0 fast path, y0 via sc1 as passenger; one vmcnt each
// iteration; every 4th iteration h1 also goes sc1 (cross-XCD rescue).
__device__ __forceinline__ void poll_dual16(const float* ph, const float* py,
                                            unsigned tgh, unsigned tgy,
                                            uint4& qh, uint4& qy) {
  for (unsigned it = 0; ; ++it) {
    if ((it & 3) != 3) {
      asm volatile("global_load_dwordx4 %0, %2, off sc0\n\t"
                   "global_load_dwordx4 %1, %3, off sc0 sc1\n\t"
                   "s_waitcnt vmcnt(0)"
                   : "=&v"(qh), "=&v"(qy) : "v"(ph), "v"(py) : "memory");
    } else {
      asm volatile("global_load_dwordx4 %0, %2, off sc0 sc1\n\t"
                   "global_load_dwordx4 %1, %3, off sc0 sc1\n\t"
                   "s_waitcnt vmcnt(0)"
                   : "=&v"(qh), "=&v"(qy) : "v"(ph), "v"(py) : "memory");
    }
    if (qh.y == tgh && qh.w == tgh && qy.y == tgy && qy.w == tgy) break;
    if (it > (1u<<20)) break;
  }
}

// ------------- embedding gather + layer0 input projection + tag zero -------
__global__ void emb_proj_k(const float* __restrict__ enc, const int* __restrict__ inp,
                           const float* __restrict__ Wih0, const float* __restrict__ bih0,
                           const float* __restrict__ bhh0, float* __restrict__ xw0,
                           float* __restrict__ hqz)
{
  __shared__ float xl[100];
  const int t = blockIdx.x;
  const int tid = threadIdx.x;
  // zero all {h,tag} pairs + election scoreboard (LLC-visible)
  for (size_t i = (size_t)t*256 + tid; i < (size_t)NZPAIRS; i += (size_t)TT*256)
    store_pair_llc(hqz + i*2, 0.f, 0u);
  if (tid < 100) {
    int q = t*100 + tid;
    int s = q / 1200;
    int rm = q - s*1200;
    int bb = rm / 300;
    int e  = rm - bb*300;
    int tok = inp[bb*25 + s];
    xl[tid] = enc[(long)tok*300 + e];
  }
  __syncthreads();
  for (int rr = 0; rr < 4; ++rr) {
    int row = rr*256 + tid;
    const float* wr = Wih0 + row*25;
    float bias = bih0[row] + bhh0[row];
    float a0 = bias, a1 = bias, a2 = bias, a3 = bias;
#pragma unroll
    for (int i = 0; i < 25; ++i) {
      float w = wr[i];
      a0 += w * xl[i];
      a1 += w * xl[25+i];
      a2 += w * xl[50+i];
      a3 += w * xl[75+i];
    }
    xw0[(t*4+0)*1024 + row] = a0;
    xw0[(t*4+1)*1024 + row] = a1;
    xw0[(t*4+2)*1024 + row] = a2;
    xw0[(t*4+3)*1024 + row] = a3;
  }
}

// ---------------- persistent 2-layer LSTM scan, fp16 MFMA ------------------
// 32 WGs launched; runtime election by XCC_ID picks 6 (2 L0 + 4 L1) so each
// layer's self-recurrence syncs through ONE shared XCD L2 (sc0). Dual-store +
// sc1-fallback polls keep any pairing correct. y0 (L0->L1, possibly cross-XCD)
// rides as a passenger load on each h1 poll iteration (sc1).
__global__ __launch_bounds__(512, 1) void scan_k(
    const float* __restrict__ Whh0, const float* __restrict__ Wih1,
    const float* __restrict__ Whh1, const float* __restrict__ bih1,
    const float* __restrict__ bhh1, const float* __restrict__ h0in,
    const float* __restrict__ c0in, const float* __restrict__ xw0,
    float* __restrict__ hq0, float* __restrict__ hq1,
    int* __restrict__ elect, float* __restrict__ dout)
{
  const int wid = blockIdx.x;
  const int tid = threadIdx.x;

  // ---- election: publish XCC id, snapshot all, compute identical roles ----
  __shared__ int evals[NLW];
  if (tid == 0) {
    int xcc = 0;
    asm volatile("s_getreg_b32 %0, hwreg(HW_REG_XCC_ID)" : "=s"(xcc));
    __hip_atomic_store(&elect[wid], (xcc & 0xff) + 1,
                       __ATOMIC_RELAXED, __HIP_MEMORY_SCOPE_AGENT);
    for (int i = 0; i < NLW; ++i) {
      int v; unsigned gd = 0;
      do { v = ld_i32_llc(&elect[i]); } while (!v && ++gd < (1u<<22));
      evals[i] = v;
    }
  }
  __syncthreads();
  int quad0,quad1,quad2,quad3, pr0,pr1;
  {
    int v4 = 0;
    for (int i = 0; i < NLW && !v4; ++i) {
      if (!evals[i]) continue;
      int c = 0;
      for (int k = 0; k < NLW; ++k) c += (evals[k] == evals[i]);
      if (c >= 4) v4 = evals[i];
    }
    if (v4) {
      int n = 0, q[4];
      for (int k = 0; k < NLW && n < 4; ++k) if (evals[k] == v4) q[n++] = k;
      quad0=q[0]; quad1=q[1]; quad2=q[2]; quad3=q[3];
    } else { quad0=0; quad1=1; quad2=2; quad3=3; }
    int v2 = 0;
    for (int i = 0; i < NLW && !v2; ++i) {
      if (i==quad0||i==quad1||i==quad2||i==quad3 || !evals[i]) continue;
      int c = 0;
      for (int k = 0; k < NLW; ++k) {
        bool kq = (k==quad0||k==quad1||k==quad2||k==quad3);
        c += (!kq && evals[k] == evals[i]);
      }
      if (c >= 2) v2 = evals[i];
    }
    int n = 0, p[2] = {-1,-1};
    for (int k = 0; k < NLW && n < 2; ++k) {
      bool kq = (k==quad0||k==quad1||k==quad2||k==quad3);
      if (kq) continue;
      if (v2 ? (evals[k] == v2) : true) p[n++] = k;
    }
    pr0 = p[0]; pr1 = p[1];
  }
  int role;
  if      (wid == pr0)   role = 0;
  else if (wid == pr1)   role = 1;
  else if (wid == quad0) role = 2;
  else if (wid == quad1) role = 3;
  else if (wid == quad2) role = 4;
  else if (wid == quad3) role = 5;
  else return;

  const int layer = (role < 2) ? 0 : 1;
  const int wid_l = layer ? (role - 2) : role;

  const int lane = tid & 63;
  const int wv   = tid >> 6;          // wave 0..7
  const int ln15 = lane & 15;
  const int kg   = lane >> 4;

  __shared__ _Float16 hb[16][520];
  __shared__ float    gl[512*5 + 4];

  // ---- weight fragments, fp16 (resident in unified VGPR/AGPR file) -------
  f16x8 wf[32];
  if (layer == 0) {
#pragma unroll
    for (int q = 0; q < 4; ++q) {
      int r = (wv*4 + q)*16 + ln15;
      int g = r >> 7, ul2 = r & 127;
      const float* wr = Whh0 + (size_t)(g*256 + wid_l*128 + ul2)*256;
#pragma unroll
      for (int kt = 0; kt < 8; ++kt) {
        f16x8 f;
#pragma unroll
        for (int jj = 0; jj < 8; ++jj) f[jj] = (_Float16)wr[kt*32 + kg*8 + jj];
        wf[q*8 + kt] = f;
      }
    }
  } else {
#pragma unroll
    for (int q = 0; q < 2; ++q) {
      int r = (wv*2 + q)*16 + ln15;
      int g = r >> 6, ul2 = r & 63;
      size_t grow = (size_t)(g*256 + wid_l*64 + ul2);
      const float* wi = Wih1 + grow*256;
      const float* wh = Whh1 + grow*256;
#pragma unroll
      for (int kt = 0; kt < 16; ++kt) {
        const float* wr = (kt < 8) ? (wi + kt*32) : (wh + (kt-8)*32);
        f16x8 f;
#pragma unroll
        for (int jj = 0; jj < 8; ++jj) f[jj] = (_Float16)wr[kg*8 + jj];
        wf[q*16 + kt] = f;
      }
    }
  }

  // ---- gate-math thread state ---------------------------------------------
  const int ul = tid >> 2, b = tid & 3;
  const bool gthr = (layer == 0) ? true : (tid < 256);
  int gu = 0; float cpr = 0.f, bs0=0.f, bs1=0.f, bs2=0.f, bs3=0.f;
  if (gthr) {
    gu = (layer == 0) ? (wid_l*128 + ul) : (wid_l*64 + ul);
    cpr = c0in[layer*1024 + b*256 + gu];
    if (layer == 1) {
      bs0 = bih1[0*256+gu] + bhh1[0*256+gu];
      bs1 = bih1[1*256+gu] + bhh1[1*256+gu];
      bs2 = bih1[2*256+gu] + bhh1[2*256+gu];
      bs3 = bih1[3*256+gu] + bhh1[3*256+gu];
    }
  }

  for (int i = tid; i < 12*520; i += 512) hb[4 + i/520][i%520] = (_Float16)0.f;

  const int UN = layer ? 64 : 128;

  for (int t = 0; t < TT; ++t) {
    float xwa=0.f, xwb=0.f, xwc=0.f, xwd=0.f;
    if (layer == 0) {
      const float* xp = xw0 + (size_t)(t*4 + b)*1024 + gu;
      xwa = xp[0]; xwb = xp[256]; xwc = xp[512]; xwd = xp[768];
    }

    // -- poll fused {h,tag}, stage to hb as fp16
    const int j  = tid >> 1;
    const int b0 = (tid & 1) * 2;
    if (layer == 0) {
      float2 v;
      if (t == 0) {
        v.x = h0in[(b0+0)*256 + j];
        v.y = h0in[(b0+1)*256 + j];
      } else {
        const float* pp = hq0 + ((size_t)(t-1)*1024 + (size_t)tid*2)*2;
        uint4 q = poll_pair16(pp, (unsigned)t);
        v.x = __uint_as_float(q.x); v.y = __uint_as_float(q.z);
      }
      hb[b0+0][j] = (_Float16)v.x;
      hb[b0+1][j] = (_Float16)v.y;
    } else {
      const float* py = hq0 + ((size_t)t*1024 + (size_t)tid*2)*2;   // y0[t]
      const unsigned tgy = (unsigned)(t+1);
      float2 vy, vh;
      if (t == 0) {
        unsigned gd = 0; uint4 q;
        do { q = ld16_llc(py); }
        while ((q.y != tgy || q.w != tgy) && ++gd < (1u<<20));
        vy.x = __uint_as_float(q.x); vy.y = __uint_as_float(q.z);
        vh.x = h0in[1024 + (b0+0)*256 + j];
        vh.y = h0in[1024 + (b0+1)*256 + j];
      } else {
        const float* ph = hq1 + ((size_t)(t-1)*1024 + (size_t)tid*2)*2;
        uint4 qh, qy;
        poll_dual16(ph, py, (unsigned)t, tgy, qh, qy);
        vy.x = __uint_as_float(qy.x); vy.y = __uint_as_float(qy.z);
        vh.x = __uint_as_float(qh.x); vh.y = __uint_as_float(qh.z);
      }
      hb[b0+0][j]     = (_Float16)vy.x;
      hb[b0+1][j]     = (_Float16)vy.y;
      hb[b0+0][256+j] = (_Float16)vh.x;
      hb[b0+1][256+j] = (_Float16)vh.y;
    }
    __syncthreads();                    // B1: staging ready

    // -- MFMA over resident fp16 fragments
    if (layer == 0) {
      f32x4 acc[4];
#pragma unroll
      for (int q = 0; q < 4; ++q) acc[q] = (f32x4){0.f,0.f,0.f,0.f};
#pragma unroll
      for (int kt = 0; kt < 8; ++kt) {
        f16x8 bfr = *(const f16x8*)&hb[ln15][kt*32 + kg*8];
#pragma unroll
        for (int q = 0; q < 4; ++q)
          acc[q] = __builtin_amdgcn_mfma_f32_16x16x32_f16(wf[q*8+kt], bfr, acc[q], 0,0,0);
      }
      if (ln15 < 4) {
#pragma unroll
        for (int q = 0; q < 4; ++q)
#pragma unroll
          for (int i = 0; i < 4; ++i)
            gl[((wv*4+q)*16 + kg*4 + i)*5 + ln15] = acc[q][i];
      }
    } else {
      f32x4 acc[2];
#pragma unroll
      for (int q = 0; q < 2; ++q) acc[q] = (f32x4){0.f,0.f,0.f,0.f};
#pragma unroll
      for (int kt = 0; kt < 16; ++kt) {
        f16x8 bfr = *(const f16x8*)&hb[ln15][kt*32 + kg*8];
#pragma unroll
        for (int q = 0; q < 2; ++q)
          acc[q] = __builtin_amdgcn_mfma_f32_16x16x32_f16(wf[q*16+kt], bfr, acc[q], 0,0,0);
      }
      if (ln15 < 4) {
#pragma unroll
        for (int q = 0; q < 2; ++q)
#pragma unroll
          for (int i = 0; i < 4; ++i)
            gl[((wv*2+q)*16 + kg*4 + i)*5 + ln15] = acc[q][i];
      }
    }
    __syncthreads();                    // B2: gates ready

    // -- gate math: thread (ul,b), cell in register, dual-publish {h,tag}
    if (gthr) {
      float gi = gl[(0*UN + ul)*5 + b] + (layer ? bs0 : xwa);
      float gf = gl[(1*UN + ul)*5 + b] + (layer ? bs1 : xwb);
      float gc = gl[(2*UN + ul)*5 + b] + (layer ? bs2 : xwc);
      float go = gl[(3*UN + ul)*5 + b] + (layer ? bs3 : xwd);
      float cn = sigf(gf)*cpr + sigf(gi)*tahf(gc);
      float hn = sigf(go)*tahf(cn);
      cpr = cn;
      float* hq = layer ? hq1 : hq0;
      store_pair_dual(hq + ((size_t)t*1024 + gu*4 + b)*2, hn, (unsigned)(t+1));
      if (t == TT-1) {
        dout[400000 + layer*1024 + b*256 + gu] = hn;
        dout[400000 + 2048 + layer*1024 + b*256 + gu] = cn;
      }
    }
  }
}

// ---------------- fc + relu + vocab decode --------------------------------
__global__ void decode_k(const float* __restrict__ y1p, const float* __restrict__ fcW,
                         const float* __restrict__ fcb, const float* __restrict__ decW,
                         const float* __restrict__ decb, float* __restrict__ dout)
{
  __shared__ float y1[1024];   // [j][b]
  __shared__ float o10[40];    // [kk][b]
  const int tid = threadIdx.x;
#pragma unroll
  for (int b = 0; b < 4; ++b)
    y1[tid*4 + b] = y1p[(size_t)(tid*4 + b)*2];   // strip tags
  __syncthreads();
  if (tid < 40) {
    int kk = tid >> 2, b = tid & 3;
    float a = fcb[kk];
    for (int j = 0; j < 256; ++j) a += fcW[kk*256 + j] * y1[j*4 + b];
    o10[kk*4 + b] = fmaxf(a, 0.f);
  }
  __syncthreads();
  int v = blockIdx.x*256 + tid;
  if (v < 100000) {
    const float* dr = decW + (size_t)v*10;
    float bias = decb[v];
    float a0 = bias, a1 = bias, a2 = bias, a3 = bias;
#pragma unroll
    for (int kk = 0; kk < 10; ++kk) {
      float w = dr[kk];
      a0 += w * o10[kk*4+0];
      a1 += w * o10[kk*4+1];
      a2 += w * o10[kk*4+2];
      a3 += w * o10[kk*4+3];
    }
    float4 o; o.x = a0; o.y = a1; o.z = a2; o.w = a3;
    ((float4*)dout)[v] = o;   // decoded.T[v][0..3]
  }
}

extern "C" void kernel_launch(void* const* d_in, const int* in_sizes, int n_in,
                              void* d_out, int out_size, void* d_ws, size_t ws_size,
                              hipStream_t stream)
{
  const float* enc  = (const float*)d_in[0];
  const float* h0in = (const float*)d_in[1];
  const float* c0in = (const float*)d_in[2];
  const float* Wih0 = (const float*)d_in[3];
  const float* Whh0 = (const float*)d_in[4];
  const float* bih0 = (const float*)d_in[5];
  const float* bhh0 = (const float*)d_in[6];
  const float* Wih1 = (const float*)d_in[7];
  const float* Whh1 = (const float*)d_in[8];
  const float* bih1 = (const float*)d_in[9];
  const float* bhh1 = (const float*)d_in[10];
  const float* fcW  = (const float*)d_in[11];
  const float* fcb  = (const float*)d_in[12];
  const float* decW = (const float*)d_in[13];
  const float* decb = (const float*)d_in[14];
  const int*   inp  = (const int*)d_in[15];

  float* ws   = (float*)d_ws;
  float* xw0  = ws + XW0_OFF;
  float* hq0  = ws + HQ0_OFF;
  float* hq1  = ws + HQ1_OFF;
  int*   el   = (int*)(ws + EL_OFF);
  float* dout = (float*)d_out;

  emb_proj_k<<<TT, 256, 0, stream>>>(enc, inp, Wih0, bih0, bhh0, xw0, hq0);
  scan_k<<<NLW, 512, 0, stream>>>(Whh0, Wih1, Whh1, bih1, bhh1,
                                  h0in, c0in, xw0, hq0, hq1, el, dout);
  decode_k<<<(100000 + 255)/256, 256, 0, stream>>>(hq1 + (size_t)(TT-1)*1024*2,
                                                   fcW, fcb, decW, decb, dout);
}